// Round 1
// baseline (2760.595 us; speedup 1.0000x reference)
//
#include <hip/hip_runtime.h>
#include <math.h>

#define B_SZ 64
#define N_NODES 1024
#define C_DIM 128
#define KI_DIM 384
#define EDIM 16
#define DOUT 64

// ---------------------------------------------------------------------------
// Kernel 1: A = softmax(relu(E @ E^T), axis=1).  One block per row n.
// E is 64 KB -> L1/L2 cached; read from global (staging all of E in LDS
// would exceed the 64 KB static-shared limit).
// ---------------------------------------------------------------------------
__global__ __launch_bounds__(256) void compute_A_kernel(
    const float* __restrict__ E, float* __restrict__ A) {
    __shared__ float red[256];
    const int tid = threadIdx.x;
    const int n = blockIdx.x;

    float en[EDIM];
#pragma unroll
    for (int e = 0; e < EDIM; ++e) en[e] = E[n * EDIM + e];

    float logit[4];
    float lmax = -1e30f;
#pragma unroll
    for (int j = 0; j < 4; ++j) {
        const int m = tid + j * 256;
        float d = 0.f;
#pragma unroll
        for (int e = 0; e < EDIM; ++e) d += en[e] * E[m * EDIM + e];
        d = fmaxf(d, 0.f);
        logit[j] = d;
        lmax = fmaxf(lmax, d);
    }
    red[tid] = lmax;
    __syncthreads();
    for (int s = 128; s > 0; s >>= 1) {
        if (tid < s) red[tid] = fmaxf(red[tid], red[tid + s]);
        __syncthreads();
    }
    lmax = red[0];
    __syncthreads();

    float ex[4];
    float lsum = 0.f;
#pragma unroll
    for (int j = 0; j < 4; ++j) {
        ex[j] = __expf(logit[j] - lmax);
        lsum += ex[j];
    }
    red[tid] = lsum;
    __syncthreads();
    for (int s = 128; s > 0; s >>= 1) {
        if (tid < s) red[tid] += red[tid + s];
        __syncthreads();
    }
    const float inv = 1.f / red[0];
#pragma unroll
    for (int j = 0; j < 4; ++j) A[n * N_NODES + tid + j * 256] = ex[j] * inv;
}

// ---------------------------------------------------------------------------
// Kernel 2: build T0 slice of xg: xg[n][b][0:128] = concat(x, state)[b][n][:]
// ---------------------------------------------------------------------------
__global__ __launch_bounds__(256) void build_T0_kernel(
    const float* __restrict__ x, const float* __restrict__ state,
    float* __restrict__ xg) {
    const int idx = blockIdx.x * 256 + threadIdx.x;  // over N*B*C
    const int c = idx & 127;
    const int nb = idx >> 7;
    const int b = nb & 63;
    const int n = nb >> 6;
    const float v = (c < 64) ? x[(b * N_NODES + n) * 64 + c]
                             : state[(b * N_NODES + n) * 64 + (c - 64)];
    xg[((size_t)n * B_SZ + b) * KI_DIM + c] = v;
}

// ---------------------------------------------------------------------------
// Kernel 3: big GEMM over the graph dimension.
//   OUT[n, b, c] = sum_m A[n,m] * IN[m, b, c]        (MODE 0)
//   OUT[n, b, c] = 2*sum(...) - xg[n, b, c(T0)]      (MODE 1, Chebyshev)
// IN/OUT are 128-wide slices of xg rows (row stride KI_DIM).
// 64x64 output tile per block, 4x4 per thread, fp32.
// ---------------------------------------------------------------------------
template <int MODE>
__global__ __launch_bounds__(256) void gemm_xg_kernel(
    const float* __restrict__ A, float* __restrict__ xg,
    int in_slot, int out_slot) {
    __shared__ float As[64][65];
    __shared__ float Bs[64][65];
    const int tid = threadIdx.x;
    const int n0 = blockIdx.x * 64;
    const int jt = blockIdx.y;  // 0..127
    const int b = jt >> 1;
    const int c0 = (jt & 1) * 64;
    const int lcol = tid & 63;
    const int lrow4 = tid >> 6;
    const int ty = tid >> 4;  // 0..15 -> rows ty*4..+3
    const int tx = tid & 15;  // cols tx*4..+3

    float acc[4][4] = {};
    for (int k0 = 0; k0 < N_NODES; k0 += 64) {
#pragma unroll
        for (int i = 0; i < 16; ++i) {
            const int r = lrow4 + i * 4;
            As[r][lcol] = A[(n0 + r) * N_NODES + k0 + lcol];
        }
#pragma unroll
        for (int i = 0; i < 16; ++i) {
            const int r = lrow4 + i * 4;
            Bs[r][lcol] =
                xg[((size_t)(k0 + r) * B_SZ + b) * KI_DIM + in_slot + c0 + lcol];
        }
        __syncthreads();
#pragma unroll
        for (int kk = 0; kk < 64; ++kk) {
            float a[4], bb[4];
#pragma unroll
            for (int i = 0; i < 4; ++i) a[i] = As[ty * 4 + i][kk];
#pragma unroll
            for (int j = 0; j < 4; ++j) bb[j] = Bs[kk][tx * 4 + j];
#pragma unroll
            for (int i = 0; i < 4; ++i)
#pragma unroll
                for (int j = 0; j < 4; ++j) acc[i][j] += a[i] * bb[j];
        }
        __syncthreads();
    }

#pragma unroll
    for (int i = 0; i < 4; ++i) {
        const int n = n0 + ty * 4 + i;
        const size_t base = ((size_t)n * B_SZ + b) * KI_DIM;
#pragma unroll
        for (int j = 0; j < 4; ++j) {
            const int c = c0 + tx * 4 + j;
            float v = acc[i][j];
            if (MODE == 1) v = 2.f * v - xg[base + c];  // 2*A@T1 - T0
            xg[base + out_slot + c] = v;
        }
    }
}

// ---------------------------------------------------------------------------
// Kernel 4: per-node gate GEMM + sigmoid + fused candidate build.
//   zr[b,o] = sigmoid( sum_ki xg[n,b,ki] * W_n[ki,o] + b_n[o] ),
//   W_n = sum_e E[n,e] * gate_W_pool[e], formed per 64-wide ki chunk in LDS.
//   o<64  -> z: overwrite xg[n][b][64+o] = z*state  (candidate slice)
//   o>=64 -> r: store to rbuf[n][b][o-64]
// One block per node. 64(b) x 128(o) outputs, 4x8 per thread.
// ---------------------------------------------------------------------------
__global__ __launch_bounds__(256) void pernode_gate_kernel(
    const float* __restrict__ E, const float* __restrict__ Wp,
    const float* __restrict__ bp, const float* __restrict__ state,
    float* __restrict__ xg, float* __restrict__ rbuf) {
    __shared__ float Xs[64][65];   // [b][kk]
    __shared__ float Ws[64][129];  // [kk][o]
    const int n = blockIdx.x;
    const int tid = threadIdx.x;
    const int ty = tid >> 4;  // b rows ty*4..+3
    const int tx = tid & 15;  // o cols tx + 16*j

    float en[EDIM];
#pragma unroll
    for (int e = 0; e < EDIM; ++e) en[e] = E[n * EDIM + e];

    float acc[4][8] = {};
    const int lcol = tid & 63;
    const int lrow4 = tid >> 6;

    for (int ki0 = 0; ki0 < KI_DIM; ki0 += 64) {
#pragma unroll
        for (int i = 0; i < 16; ++i) {
            const int bb = lrow4 + i * 4;
            Xs[bb][lcol] = xg[((size_t)n * B_SZ + bb) * KI_DIM + ki0 + lcol];
        }
        // form W_n chunk: 64 x 128 elements, 32 per thread (o-inner, coalesced)
#pragma unroll 4
        for (int i = 0; i < 32; ++i) {
            const int idx = tid + i * 256;
            const int kk = idx >> 7;
            const int o = idx & 127;
            float w = 0.f;
#pragma unroll
            for (int e = 0; e < EDIM; ++e)
                w += en[e] * Wp[e * (3 * 128 * 128) + (ki0 + kk) * 128 + o];
            Ws[kk][o] = w;
        }
        __syncthreads();
#pragma unroll
        for (int kk = 0; kk < 64; ++kk) {
            float xv[4], wv[8];
#pragma unroll
            for (int i = 0; i < 4; ++i) xv[i] = Xs[ty * 4 + i][kk];
#pragma unroll
            for (int j = 0; j < 8; ++j) wv[j] = Ws[kk][tx + 16 * j];
#pragma unroll
            for (int i = 0; i < 4; ++i)
#pragma unroll
                for (int j = 0; j < 8; ++j) acc[i][j] += xv[i] * wv[j];
        }
        __syncthreads();
    }

    float bias[8];
#pragma unroll
    for (int j = 0; j < 8; ++j) {
        const int o = tx + 16 * j;
        float bv = 0.f;
#pragma unroll
        for (int e = 0; e < EDIM; ++e) bv += en[e] * bp[e * 128 + o];
        bias[j] = bv;
    }

#pragma unroll
    for (int i = 0; i < 4; ++i) {
        const int b = ty * 4 + i;
#pragma unroll
        for (int j = 0; j < 8; ++j) {
            const int o = tx + 16 * j;
            const float v = 1.f / (1.f + __expf(-(acc[i][j] + bias[j])));
            if (o < 64) {  // z -> candidate slice
                const float s = state[(b * N_NODES + n) * 64 + o];
                xg[((size_t)n * B_SZ + b) * KI_DIM + 64 + o] = v * s;
            } else {  // r
                rbuf[((size_t)n * B_SZ + b) * 64 + (o - 64)] = v;
            }
        }
    }
}

// ---------------------------------------------------------------------------
// Kernel 5: per-node update GEMM + tanh + final GRU combine -> d_out.
//   hc = tanh(xg_n @ Wu_n + bu_n); out = r*state + (1-r)*hc
// One block per node. 64(b) x 64(o) outputs, 4x4 per thread.
// ---------------------------------------------------------------------------
__global__ __launch_bounds__(256) void pernode_upd_kernel(
    const float* __restrict__ E, const float* __restrict__ Wp,
    const float* __restrict__ bp, const float* __restrict__ state,
    const float* __restrict__ xg, const float* __restrict__ rbuf,
    float* __restrict__ out) {
    __shared__ float Xs[64][65];  // [b][kk]
    __shared__ float Ws[64][65];  // [kk][o]
    const int n = blockIdx.x;
    const int tid = threadIdx.x;
    const int ty = tid >> 4;  // b rows ty*4..+3
    const int tx = tid & 15;  // o cols tx + 16*j

    float en[EDIM];
#pragma unroll
    for (int e = 0; e < EDIM; ++e) en[e] = E[n * EDIM + e];

    float acc[4][4] = {};
    const int lcol = tid & 63;
    const int lrow4 = tid >> 6;

    for (int ki0 = 0; ki0 < KI_DIM; ki0 += 64) {
#pragma unroll
        for (int i = 0; i < 16; ++i) {
            const int bb = lrow4 + i * 4;
            Xs[bb][lcol] = xg[((size_t)n * B_SZ + bb) * KI_DIM + ki0 + lcol];
        }
        // form W_n chunk: 64 x 64 elements, 16 per thread
#pragma unroll 4
        for (int i = 0; i < 16; ++i) {
            const int idx = tid + i * 256;
            const int kk = idx >> 6;
            const int o = idx & 63;
            float w = 0.f;
#pragma unroll
            for (int e = 0; e < EDIM; ++e)
                w += en[e] * Wp[e * (3 * 128 * 64) + (ki0 + kk) * 64 + o];
            Ws[kk][o] = w;
        }
        __syncthreads();
#pragma unroll
        for (int kk = 0; kk < 64; ++kk) {
            float xv[4], wv[4];
#pragma unroll
            for (int i = 0; i < 4; ++i) xv[i] = Xs[ty * 4 + i][kk];
#pragma unroll
            for (int j = 0; j < 4; ++j) wv[j] = Ws[kk][tx + 16 * j];
#pragma unroll
            for (int i = 0; i < 4; ++i)
#pragma unroll
                for (int j = 0; j < 4; ++j) acc[i][j] += xv[i] * wv[j];
        }
        __syncthreads();
    }

    float bias[4];
#pragma unroll
    for (int j = 0; j < 4; ++j) {
        const int o = tx + 16 * j;
        float bv = 0.f;
#pragma unroll
        for (int e = 0; e < EDIM; ++e) bv += en[e] * bp[e * 64 + o];
        bias[j] = bv;
    }

#pragma unroll
    for (int i = 0; i < 4; ++i) {
        const int b = ty * 4 + i;
#pragma unroll
        for (int j = 0; j < 4; ++j) {
            const int o = tx + 16 * j;
            const float hc = tanhf(acc[i][j] + bias[j]);
            const float r = rbuf[((size_t)n * B_SZ + b) * 64 + o];
            const float s = state[(b * N_NODES + n) * 64 + o];
            out[(b * N_NODES + n) * 64 + o] = r * s + (1.f - r) * hc;
        }
    }
}

// ---------------------------------------------------------------------------
extern "C" void kernel_launch(void* const* d_in, const int* in_sizes, int n_in,
                              void* d_out, int out_size, void* d_ws,
                              size_t ws_size, hipStream_t stream) {
    const float* x = (const float*)d_in[0];      // (64,1024,64)
    const float* state = (const float*)d_in[1];  // (64,1024,64)
    const float* E = (const float*)d_in[2];      // (1024,16)
    const float* gW = (const float*)d_in[3];     // (16,3,128,128)
    const float* gb = (const float*)d_in[4];     // (16,128)
    const float* uW = (const float*)d_in[5];     // (16,3,128,64)
    const float* ub = (const float*)d_in[6];     // (16,64)
    float* out = (float*)d_out;

    float* ws = (float*)d_ws;
    float* A = ws;                                        // 1024*1024
    float* xg = A + (size_t)N_NODES * N_NODES;            // 1024*64*384
    float* rbuf = xg + (size_t)N_NODES * B_SZ * KI_DIM;   // 1024*64*64
    // total: 30,408,704 floats = 121.6 MB of ws

    compute_A_kernel<<<N_NODES, 256, 0, stream>>>(E, A);
    build_T0_kernel<<<(N_NODES * B_SZ * C_DIM) / 256, 256, 0, stream>>>(
        x, state, xg);

    // --- avwgcn #1 (gate) ---
    gemm_xg_kernel<0><<<dim3(16, 128), 256, 0, stream>>>(A, xg, 0, 128);
    gemm_xg_kernel<1><<<dim3(16, 128), 256, 0, stream>>>(A, xg, 128, 256);
    pernode_gate_kernel<<<N_NODES, 256, 0, stream>>>(E, gW, gb, state, xg,
                                                     rbuf);

    // --- avwgcn #2 (update); T0 now holds candidate = [x, z*state] ---
    gemm_xg_kernel<0><<<dim3(16, 128), 256, 0, stream>>>(A, xg, 0, 128);
    gemm_xg_kernel<1><<<dim3(16, 128), 256, 0, stream>>>(A, xg, 128, 256);
    pernode_upd_kernel<<<N_NODES, 256, 0, stream>>>(E, uW, ub, state, xg, rbuf,
                                                    out);
}

// Round 3
// 442.521 us; speedup vs baseline: 6.2383x; 6.2383x over previous
//
#include <hip/hip_runtime.h>
#include <math.h>

#define N_NODES 1024
#define B_SZ 64
#define GN 8192      // b*c flattened width of xg slot buffers
#define KI 384       // 3*128
#define EDIM 16

typedef _Float16 half8_t __attribute__((ext_vector_type(8)));
typedef float f32x4 __attribute__((ext_vector_type(4)));

__device__ __forceinline__ unsigned short f2h(float f) {
    _Float16 h = (_Float16)f;
    return *(unsigned short*)&h;
}
__device__ __forceinline__ float h2f(unsigned short u) {
    _Float16 h = *(_Float16*)&u;
    return (float)h;
}
__device__ __forceinline__ float sigmoidf_(float v) {
    return 1.f / (1.f + __expf(-v));
}

// ---------------------------------------------------------------------------
// A = softmax(relu(E E^T)) row-wise -> fp16
// ---------------------------------------------------------------------------
__global__ __launch_bounds__(256) void compute_A_kernel(
    const float* __restrict__ E, unsigned short* __restrict__ Ah) {
    __shared__ float red[256];
    const int tid = threadIdx.x;
    const int n = blockIdx.x;
    float en[EDIM];
#pragma unroll
    for (int e = 0; e < EDIM; ++e) en[e] = E[n * EDIM + e];
    float logit[4], lmax = -1e30f;
#pragma unroll
    for (int j = 0; j < 4; ++j) {
        const int m = tid + j * 256;
        float d = 0.f;
#pragma unroll
        for (int e = 0; e < EDIM; ++e) d += en[e] * E[m * EDIM + e];
        d = fmaxf(d, 0.f);
        logit[j] = d;
        lmax = fmaxf(lmax, d);
    }
    red[tid] = lmax;
    __syncthreads();
    for (int s = 128; s > 0; s >>= 1) {
        if (tid < s) red[tid] = fmaxf(red[tid], red[tid + s]);
        __syncthreads();
    }
    lmax = red[0];
    __syncthreads();
    float ex[4], lsum = 0.f;
#pragma unroll
    for (int j = 0; j < 4; ++j) {
        ex[j] = __expf(logit[j] - lmax);
        lsum += ex[j];
    }
    red[tid] = lsum;
    __syncthreads();
    for (int s = 128; s > 0; s >>= 1) {
        if (tid < s) red[tid] += red[tid + s];
        __syncthreads();
    }
    const float inv = 1.f / red[0];
#pragma unroll
    for (int j = 0; j < 4; ++j)
        Ah[n * N_NODES + tid + j * 256] = f2h(ex[j] * inv);
}

// ---------------------------------------------------------------------------
// T0[n][b*128+c] = concat(x,state)[b][n][c]  (fp16)
// ---------------------------------------------------------------------------
__global__ __launch_bounds__(256) void build_T0_kernel(
    const float* __restrict__ x, const float* __restrict__ state,
    unsigned short* __restrict__ T0) {
    const int n = blockIdx.x;
    const int tid = threadIdx.x;
#pragma unroll
    for (int t = 0; t < 32; ++t) {
        const int idx = t * 256 + tid;
        const int c = idx & 127;
        const int b = idx >> 7;
        const float v = (c < 64) ? x[((size_t)b * N_NODES + n) * 64 + c]
                                 : state[((size_t)b * N_NODES + n) * 64 + (c - 64)];
        T0[(size_t)n * GN + idx] = f2h(v);
    }
}

// ---------------------------------------------------------------------------
// Graph GEMM: OUT[n][bc] = sum_m A[n][m] * IN[m][bc]   (MODE1: 2*acc - T0)
// fp16 MFMA 16x16x32, 128x128 block tile, BK=64, 4 waves (2x2 of 64x64).
// B staged transposed into LDS (Bs[bc][m]) so frag reads are ds_read_b128.
// ---------------------------------------------------------------------------
template <int MODE>
__global__ __launch_bounds__(256) void gemm_graph_kernel(
    const unsigned short* __restrict__ Ah,
    const unsigned short* __restrict__ IN,
    const unsigned short* __restrict__ T0ref,
    unsigned short* __restrict__ OUT) {
    __shared__ unsigned short As[128 * 64];  // [n-local][k]
    __shared__ unsigned short Bs[128 * 64];  // [bc-local][k]  (transposed)
    const int tid = threadIdx.x;
    const int wave = tid >> 6;
    const int lane = tid & 63;
    const int l15 = lane & 15;
    const int quad = lane >> 4;
    const int wm = (wave >> 1) * 64;
    const int wn = (wave & 1) * 64;
    const int n0 = blockIdx.x * 128;
    const int bc0 = blockIdx.y * 128;

    f32x4 acc[4][4] = {};

    for (int k0 = 0; k0 < N_NODES; k0 += 64) {
        // --- stage A (natural layout, rows k-contiguous) ---
#pragma unroll
        for (int t = 0; t < 4; ++t) {
            const int id = t * 256 + tid;
            const int row = id >> 3;
            const int c8 = id & 7;
            *(uint4*)&As[row * 64 + c8 * 8] =
                *(const uint4*)&Ah[(size_t)(n0 + row) * N_NODES + k0 + c8 * 8];
        }
        // --- stage B transposed: read 2 rows x 8 cols, write 8 packed b32 ---
#pragma unroll
        for (int t = 0; t < 2; ++t) {
            const int id = t * 256 + tid;
            const int r2 = id & 31;       // pair of k-rows: m = 2*r2, 2*r2+1
            const int c8 = id >> 5;       // 0..15
            const unsigned short* g =
                &IN[(size_t)(k0 + 2 * r2) * GN + bc0 + c8 * 8];
            uint4 lo = *(const uint4*)g;
            uint4 hi = *(const uint4*)(g + GN);
            const unsigned short* ls = (const unsigned short*)&lo;
            const unsigned short* hs = (const unsigned short*)&hi;
#pragma unroll
            for (int j = 0; j < 8; ++j) {
                const int c = c8 * 8 + j;
                const unsigned int w =
                    (unsigned int)ls[j] | ((unsigned int)hs[j] << 16);
                *(unsigned int*)&Bs[c * 64 + 2 * r2] = w;
            }
        }
        __syncthreads();
#pragma unroll
        for (int ks = 0; ks < 2; ++ks) {
            half8_t a[4], b[4];
#pragma unroll
            for (int mi = 0; mi < 4; ++mi)
                a[mi] = *(const half8_t*)&As[(wm + mi * 16 + l15) * 64 +
                                             ks * 32 + quad * 8];
#pragma unroll
            for (int ni = 0; ni < 4; ++ni)
                b[ni] = *(const half8_t*)&Bs[(wn + ni * 16 + l15) * 64 +
                                             ks * 32 + quad * 8];
#pragma unroll
            for (int mi = 0; mi < 4; ++mi)
#pragma unroll
                for (int ni = 0; ni < 4; ++ni)
                    acc[mi][ni] = __builtin_amdgcn_mfma_f32_16x16x32_f16(
                        a[mi], b[ni], acc[mi][ni], 0, 0, 0);
        }
        __syncthreads();
    }

#pragma unroll
    for (int mi = 0; mi < 4; ++mi) {
#pragma unroll
        for (int ni = 0; ni < 4; ++ni) {
#pragma unroll
            for (int r = 0; r < 4; ++r) {
                const int n_g = n0 + wm + mi * 16 + quad * 4 + r;
                const int bc_g = bc0 + wn + ni * 16 + l15;
                float v = acc[mi][ni][r];
                if (MODE == 1)
                    v = 2.f * v - h2f(T0ref[(size_t)n_g * GN + bc_g]);
                OUT[(size_t)n_g * GN + bc_g] = f2h(v);
            }
        }
    }
}

// ---------------------------------------------------------------------------
// Dequant: Wt[n][o][ki] = sum_e E[n,e]*Wp[e][ki][o_off+o]  (fp16, k-contig)
// Block: 32 ki x 16 o x 64 n; W_pool patch staged once in LDS, reused over n.
// ---------------------------------------------------------------------------
__global__ __launch_bounds__(256) void dequant_kernel(
    const float* __restrict__ Wp, const float* __restrict__ E,
    unsigned short* __restrict__ Wt, int OWtot, int o_off) {
    __shared__ float Lw[16 * 16 * 36];  // [e][o][ki padded to 36]
    __shared__ float En[64 * 17];
    const int tid = threadIdx.x;
    const int ki0 = blockIdx.x * 32;
    const int o0 = blockIdx.y * 16;
    const int n0 = blockIdx.z * 64;

#pragma unroll
    for (int t = 0; t < 4; ++t) {
        const int id = t * 256 + tid;
        const int e = id & 15;
        const int nl = id >> 4;
        En[nl * 17 + e] = E[(n0 + nl) * EDIM + e];
    }
#pragma unroll
    for (int t = 0; t < 32; ++t) {
        const int id = t * 256 + tid;
        const int o = id & 15;
        const int ki = (id >> 4) & 31;
        const int e = id >> 9;
        Lw[(e * 16 + o) * 36 + ki] =
            Wp[(size_t)(e * KI + ki0 + ki) * OWtot + o_off + o0 + o];
    }
    __syncthreads();

    const int n_l = tid & 63;
    const int grp = tid >> 6;
    float en[EDIM];
#pragma unroll
    for (int e = 0; e < EDIM; ++e) en[e] = En[n_l * 17 + e];

#pragma unroll 4
    for (int i = 0; i < 32; ++i) {
        const int cell = grp + i * 4;   // 0..127
        const int o = cell >> 3;        // 0..15
        const int k4 = cell & 7;        // 0..7 -> 4 ki each
        f32x4 a = {0.f, 0.f, 0.f, 0.f};
#pragma unroll
        for (int e = 0; e < EDIM; ++e) {
            const f32x4 w = *(const f32x4*)&Lw[(e * 16 + o) * 36 + k4 * 4];
            a += en[e] * w;
        }
        union { unsigned short u[4]; uint2 v; } pk;
#pragma unroll
        for (int j = 0; j < 4; ++j) pk.u[j] = f2h(a[j]);
        *(uint2*)&Wt[((size_t)(n0 + n_l) * 64 + (o0 + o)) * KI + ki0 + k4 * 4] =
            pk.v;
    }
}

// ---------------------------------------------------------------------------
// Per-node GEMM + epilogue. MODE 0=R (store r), 1=Z (T0 state-slice = z*state),
// 2=U (out = r*state + (1-r)*tanh(acc+bias)).  M=64(b) N=64(o) K=384, MFMA.
// ---------------------------------------------------------------------------
template <int MODE>
__global__ __launch_bounds__(256) void pernode_kernel(
    const unsigned short* __restrict__ T0,
    const unsigned short* __restrict__ T1,
    const unsigned short* __restrict__ T2,
    const unsigned short* __restrict__ Wt, const float* __restrict__ E,
    const float* __restrict__ bp, int bp_stride, int o_off,
    const float* __restrict__ state, float* __restrict__ rbuf,
    unsigned short* __restrict__ t0_out, float* __restrict__ out) {
    __shared__ unsigned short Xs[64 * 128];  // [b][k]
    __shared__ unsigned short Ws[64 * 128];  // [o][k]
    const int n = blockIdx.x;
    const int tid = threadIdx.x;
    const int wave = tid >> 6;
    const int lane = tid & 63;
    const int l15 = lane & 15;
    const int quad = lane >> 4;
    const int wn = wave * 16;
    const int o_g = wn + l15;

    float bias = 0.f;
#pragma unroll
    for (int e = 0; e < EDIM; ++e)
        bias += E[n * EDIM + e] * bp[e * bp_stride + o_off + o_g];

    f32x4 acc[4] = {};

    for (int s = 0; s < 3; ++s) {
        const unsigned short* Ts = (s == 0) ? T0 : (s == 1) ? T1 : T2;
#pragma unroll
        for (int t = 0; t < 4; ++t) {
            const int id = t * 256 + tid;
            const int c8 = id & 15;
            const int b = id >> 4;
            *(uint4*)&Xs[b * 128 + c8 * 8] =
                *(const uint4*)&Ts[(size_t)n * GN + b * 128 + c8 * 8];
        }
#pragma unroll
        for (int t = 0; t < 4; ++t) {
            const int id = t * 256 + tid;
            const int k8 = id & 15;
            const int o = id >> 4;
            *(uint4*)&Ws[o * 128 + k8 * 8] =
                *(const uint4*)&Wt[((size_t)n * 64 + o) * KI + s * 128 + k8 * 8];
        }
        __syncthreads();
#pragma unroll
        for (int ks = 0; ks < 4; ++ks) {
            const half8_t b =
                *(const half8_t*)&Ws[(wn + l15) * 128 + ks * 32 + quad * 8];
#pragma unroll
            for (int mi = 0; mi < 4; ++mi) {
                const half8_t a = *(const half8_t*)&Xs[(mi * 16 + l15) * 128 +
                                                       ks * 32 + quad * 8];
                acc[mi] =
                    __builtin_amdgcn_mfma_f32_16x16x32_f16(a, b, acc[mi], 0, 0, 0);
            }
        }
        __syncthreads();
    }

#pragma unroll
    for (int mi = 0; mi < 4; ++mi) {
#pragma unroll
        for (int r = 0; r < 4; ++r) {
            const int b_g = mi * 16 + quad * 4 + r;
            const float v = acc[mi][r] + bias;
            if (MODE == 0) {
                rbuf[((size_t)n * B_SZ + b_g) * 64 + o_g] = sigmoidf_(v);
            } else if (MODE == 1) {
                const float sv = state[((size_t)b_g * N_NODES + n) * 64 + o_g];
                t0_out[(size_t)n * GN + b_g * 128 + 64 + o_g] =
                    f2h(sigmoidf_(v) * sv);
            } else {
                const float hc = tanhf(v);
                const float rr = rbuf[((size_t)n * B_SZ + b_g) * 64 + o_g];
                const float sv = state[((size_t)b_g * N_NODES + n) * 64 + o_g];
                out[((size_t)b_g * N_NODES + n) * 64 + o_g] =
                    rr * sv + (1.f - rr) * hc;
            }
        }
    }
}

// ---------------------------------------------------------------------------
extern "C" void kernel_launch(void* const* d_in, const int* in_sizes, int n_in,
                              void* d_out, int out_size, void* d_ws,
                              size_t ws_size, hipStream_t stream) {
    const float* x = (const float*)d_in[0];
    const float* state = (const float*)d_in[1];
    const float* E = (const float*)d_in[2];
    const float* gW = (const float*)d_in[3];  // (16,3,128,128)
    const float* gb = (const float*)d_in[4];  // (16,128)
    const float* uW = (const float*)d_in[5];  // (16,3,128,64)
    const float* ub = (const float*)d_in[6];  // (16,64)
    float* out = (float*)d_out;

    char* ws = (char*)d_ws;
    unsigned short* Ah = (unsigned short*)ws;                   // 2 MB
    unsigned short* T0 = (unsigned short*)(ws + 2097152);       // 16.78 MB
    unsigned short* T1 = (unsigned short*)(ws + 18874368);
    unsigned short* T2 = (unsigned short*)(ws + 35651584);
    unsigned short* Wt = (unsigned short*)(ws + 52428800);      // 50.33 MB
    float* rbuf = (float*)(ws + 102760448);                     // 16.78 MB
    // total 119.5 MB

    compute_A_kernel<<<N_NODES, 256, 0, stream>>>(E, Ah);
    build_T0_kernel<<<N_NODES, 256, 0, stream>>>(x, state, T0);

    const dim3 ggrid(8, 64);
    const dim3 dqgrid(12, 4, 16);

    // --- avwgcn #1 (gate) ---
    gemm_graph_kernel<0><<<ggrid, 256, 0, stream>>>(Ah, T0, T0, T1);
    gemm_graph_kernel<1><<<ggrid, 256, 0, stream>>>(Ah, T1, T0, T2);
    // r first (z overwrites T0 state-slice)
    dequant_kernel<<<dqgrid, 256, 0, stream>>>(gW, E, Wt, 128, 64);
    pernode_kernel<0><<<N_NODES, 256, 0, stream>>>(T0, T1, T2, Wt, E, gb, 128,
                                                   64, state, rbuf, T0, out);
    dequant_kernel<<<dqgrid, 256, 0, stream>>>(gW, E, Wt, 128, 0);
    pernode_kernel<1><<<N_NODES, 256, 0, stream>>>(T0, T1, T2, Wt, E, gb, 128,
                                                   0, state, rbuf, T0, out);

    // --- avwgcn #2 (update); T0 now holds candidate = [x, z*state] ---
    gemm_graph_kernel<0><<<ggrid, 256, 0, stream>>>(Ah, T0, T0, T1);
    gemm_graph_kernel<1><<<ggrid, 256, 0, stream>>>(Ah, T1, T0, T2);
    dequant_kernel<<<dqgrid, 256, 0, stream>>>(uW, E, Wt, 64, 0);
    pernode_kernel<2><<<N_NODES, 256, 0, stream>>>(T0, T1, T2, Wt, E, ub, 64,
                                                   0, state, rbuf, T0, out);
}

// Round 4
// 377.314 us; speedup vs baseline: 7.3164x; 1.1728x over previous
//
#include <hip/hip_runtime.h>
#include <math.h>

#define N_NODES 1024
#define B_SZ 64
#define GN 8192      // b*c flattened width of xg slot buffers
#define KI 384       // 3*128
#define EDIM 16

typedef _Float16 half8_t __attribute__((ext_vector_type(8)));
typedef float f32x4 __attribute__((ext_vector_type(4)));

__device__ __forceinline__ unsigned short f2h(float f) {
    _Float16 h = (_Float16)f;
    return *(unsigned short*)&h;
}
__device__ __forceinline__ float h2f(unsigned short u) {
    _Float16 h = *(_Float16*)&u;
    return (float)h;
}
__device__ __forceinline__ float sigmoidf_(float v) {
    return 1.f / (1.f + __expf(-v));
}
// async global->LDS, 16B per lane; lds base must be wave-uniform.
__device__ __forceinline__ void load_lds16(const void* g, void* l) {
    __builtin_amdgcn_global_load_lds(
        (const __attribute__((address_space(1))) void*)g,
        (__attribute__((address_space(3))) void*)l, 16, 0, 0);
}

// ---------------------------------------------------------------------------
// A = softmax(relu(E E^T)) row-wise -> fp16
// ---------------------------------------------------------------------------
__global__ __launch_bounds__(256) void compute_A_kernel(
    const float* __restrict__ E, unsigned short* __restrict__ Ah) {
    __shared__ float red[256];
    const int tid = threadIdx.x;
    const int n = blockIdx.x;
    float en[EDIM];
#pragma unroll
    for (int e = 0; e < EDIM; ++e) en[e] = E[n * EDIM + e];
    float logit[4], lmax = -1e30f;
#pragma unroll
    for (int j = 0; j < 4; ++j) {
        const int m = tid + j * 256;
        float d = 0.f;
#pragma unroll
        for (int e = 0; e < EDIM; ++e) d += en[e] * E[m * EDIM + e];
        d = fmaxf(d, 0.f);
        logit[j] = d;
        lmax = fmaxf(lmax, d);
    }
    red[tid] = lmax;
    __syncthreads();
    for (int s = 128; s > 0; s >>= 1) {
        if (tid < s) red[tid] = fmaxf(red[tid], red[tid + s]);
        __syncthreads();
    }
    lmax = red[0];
    __syncthreads();
    float ex[4], lsum = 0.f;
#pragma unroll
    for (int j = 0; j < 4; ++j) {
        ex[j] = __expf(logit[j] - lmax);
        lsum += ex[j];
    }
    red[tid] = lsum;
    __syncthreads();
    for (int s = 128; s > 0; s >>= 1) {
        if (tid < s) red[tid] += red[tid + s];
        __syncthreads();
    }
    const float inv = 1.f / red[0];
#pragma unroll
    for (int j = 0; j < 4; ++j)
        Ah[n * N_NODES + tid + j * 256] = f2h(ex[j] * inv);
}

// ---------------------------------------------------------------------------
// T0[n][b*128+c] = concat(x,state)[b][n][c]  (fp16)
// ---------------------------------------------------------------------------
__global__ __launch_bounds__(256) void build_T0_kernel(
    const float* __restrict__ x, const float* __restrict__ state,
    unsigned short* __restrict__ T0) {
    const int n = blockIdx.x;
    const int tid = threadIdx.x;
#pragma unroll
    for (int t = 0; t < 32; ++t) {
        const int idx = t * 256 + tid;
        const int c = idx & 127;
        const int b = idx >> 7;
        const float v = (c < 64) ? x[((size_t)b * N_NODES + n) * 64 + c]
                                 : state[((size_t)b * N_NODES + n) * 64 + (c - 64)];
        T0[(size_t)n * GN + idx] = f2h(v);
    }
}

// ---------------------------------------------------------------------------
// Graph GEMM: OUT[n][bc] = sum_m A[n][m] * IN[m][bc]   (MODE1: 2*acc - T0)
// fp16 MFMA 16x16x32, 128x128 tile, BK=64. A staged via global_load_lds;
// B transposed into LDS via packed b32 writes. Epilogue: LDS repack (Cs,
// pad 136) -> uint4 coalesced stores; MODE1 reads T0 as uint4.
// ---------------------------------------------------------------------------
template <int MODE>
__global__ __launch_bounds__(256) void gemm_graph_kernel(
    const unsigned short* __restrict__ Ah,
    const unsigned short* __restrict__ IN,
    const unsigned short* __restrict__ T0ref,
    unsigned short* __restrict__ OUT) {
    __shared__ union {
        struct {
            unsigned short As[128 * 64];  // [n-local][k]
            unsigned short Bs[128 * 64];  // [bc-local][k] (transposed)
        } s;
        unsigned short Cs[128 * 136];     // epilogue repack
    } lds;
    const int tid = threadIdx.x;
    const int wave = tid >> 6;
    const int lane = tid & 63;
    const int l15 = lane & 15;
    const int quad = lane >> 4;
    const int wm = (wave >> 1) * 64;
    const int wn = (wave & 1) * 64;
    const int n0 = blockIdx.x * 128;
    const int bc0 = blockIdx.y * 128;

    f32x4 acc[4][4] = {};

    for (int k0 = 0; k0 < N_NODES; k0 += 64) {
        // --- stage A via async DMA: 4 x 1KB per wave, natural layout ---
#pragma unroll
        for (int i = 0; i < 4; ++i) {
            const int rbase = wave * 32 + i * 8;
            const unsigned short* g =
                &Ah[(size_t)(n0 + rbase + (lane >> 3)) * N_NODES + k0 +
                    (lane & 7) * 8];
            load_lds16(g, &lds.s.As[rbase * 64]);
        }
        // --- stage B transposed: read 2 rows x 8 cols, write 8 packed b32 ---
#pragma unroll
        for (int t = 0; t < 2; ++t) {
            const int id = t * 256 + tid;
            const int r2 = id & 31;       // pair of k-rows: m = 2*r2, 2*r2+1
            const int c8 = id >> 5;       // 0..15
            const unsigned short* g =
                &IN[(size_t)(k0 + 2 * r2) * GN + bc0 + c8 * 8];
            uint4 lo = *(const uint4*)g;
            uint4 hi = *(const uint4*)(g + GN);
            const unsigned short* ls = (const unsigned short*)&lo;
            const unsigned short* hs = (const unsigned short*)&hi;
#pragma unroll
            for (int j = 0; j < 8; ++j) {
                const int c = c8 * 8 + j;
                const unsigned int w =
                    (unsigned int)ls[j] | ((unsigned int)hs[j] << 16);
                *(unsigned int*)&lds.s.Bs[c * 64 + 2 * r2] = w;
            }
        }
        __syncthreads();
#pragma unroll
        for (int ks = 0; ks < 2; ++ks) {
            half8_t a[4], b[4];
#pragma unroll
            for (int mi = 0; mi < 4; ++mi)
                a[mi] = *(const half8_t*)&lds.s.As[(wm + mi * 16 + l15) * 64 +
                                                   ks * 32 + quad * 8];
#pragma unroll
            for (int ni = 0; ni < 4; ++ni)
                b[ni] = *(const half8_t*)&lds.s.Bs[(wn + ni * 16 + l15) * 64 +
                                                   ks * 32 + quad * 8];
#pragma unroll
            for (int mi = 0; mi < 4; ++mi)
#pragma unroll
                for (int ni = 0; ni < 4; ++ni)
                    acc[mi][ni] = __builtin_amdgcn_mfma_f32_16x16x32_f16(
                        a[mi], b[ni], acc[mi][ni], 0, 0, 0);
        }
        __syncthreads();
    }

    // --- epilogue: repack through LDS, coalesced uint4 stores ---
#pragma unroll
    for (int mi = 0; mi < 4; ++mi)
#pragma unroll
        for (int ni = 0; ni < 4; ++ni)
#pragma unroll
            for (int r = 0; r < 4; ++r) {
                const int row = wm + mi * 16 + quad * 4 + r;
                const int col = wn + ni * 16 + l15;
                lds.Cs[row * 136 + col] = f2h(acc[mi][ni][r]);
            }
    __syncthreads();
#pragma unroll
    for (int i = 0; i < 8; ++i) {
        const int id = i * 256 + tid;
        const int row = id >> 4;
        const int c8 = id & 15;
        uint4 cv = *(const uint4*)&lds.Cs[row * 136 + c8 * 8];
        const size_t gaddr = (size_t)(n0 + row) * GN + bc0 + c8 * 8;
        if (MODE == 1) {
            uint4 tv = *(const uint4*)&T0ref[gaddr];
            const unsigned short* cp = (const unsigned short*)&cv;
            const unsigned short* tp = (const unsigned short*)&tv;
            union { unsigned short u[8]; uint4 v; } o;
#pragma unroll
            for (int j = 0; j < 8; ++j)
                o.u[j] = f2h(2.f * h2f(cp[j]) - h2f(tp[j]));
            *(uint4*)&OUT[gaddr] = o.v;
        } else {
            *(uint4*)&OUT[gaddr] = cv;
        }
    }
}

// ---------------------------------------------------------------------------
// Dequant v2: Wt[n][o][ki] = sum_e E[n,e]*Wp[e][ki][o_off+o]  (fp16)
// Pool patch held in REGISTERS (w[16] f32x4), looped over 32 nodes/block.
// Per node: 16 broadcast ds_read_b32 + 64 v_fma — VALU-bound, not LDS-bound.
// grid (KI/32, 64/32, 1024/32); thread -> o = tid>>3, k4 = tid&7 (4 ki).
// ---------------------------------------------------------------------------
__global__ __launch_bounds__(256) void dequant_kernel(
    const float* __restrict__ Wp, const float* __restrict__ E,
    unsigned short* __restrict__ Wt, int OWtot, int o_off) {
    __shared__ float En[32 * 16];
    const int tid = threadIdx.x;
    const int ki0 = blockIdx.x * 32;
    const int o0 = blockIdx.y * 32;
    const int n0 = blockIdx.z * 32;
    const int o = tid >> 3;
    const int k4 = tid & 7;

#pragma unroll
    for (int t = 0; t < 2; ++t) {
        const int id = t * 256 + tid;
        En[id] = E[(n0 + (id >> 4)) * EDIM + (id & 15)];
    }
    __syncthreads();

    // preload pool patch into registers: 16 e x 4 ki
    f32x4 w[EDIM];
#pragma unroll
    for (int e = 0; e < EDIM; ++e) {
        f32x4 v;
#pragma unroll
        for (int j = 0; j < 4; ++j)
            v[j] = Wp[(size_t)(e * KI + ki0 + k4 * 4 + j) * OWtot + o_off +
                      o0 + o];
        w[e] = v;
    }

    const size_t wt_base =
        ((size_t)n0 * 64 + (o0 + o)) * KI + ki0 + k4 * 4;
#pragma unroll 4
    for (int nl = 0; nl < 32; ++nl) {
        f32x4 a = {0.f, 0.f, 0.f, 0.f};
#pragma unroll
        for (int e = 0; e < EDIM; ++e) a += w[e] * En[nl * EDIM + e];
        union { unsigned short u[4]; uint2 v; } pk;
#pragma unroll
        for (int j = 0; j < 4; ++j) pk.u[j] = f2h(a[j]);
        *(uint2*)&Wt[wt_base + (size_t)nl * 64 * KI] = pk.v;
    }
}

// ---------------------------------------------------------------------------
// Per-node GEMM + epilogue. MODE 0=R (store r), 1=Z (T0 state-slice = z*state),
// 2=U (out = r*state + (1-r)*tanh(acc+bias)).  M=64(b) N=64(o) K=384, MFMA.
// Xs/Ws staged via global_load_lds (both k-contiguous in global).
// ---------------------------------------------------------------------------
template <int MODE>
__global__ __launch_bounds__(256) void pernode_kernel(
    const unsigned short* __restrict__ T0,
    const unsigned short* __restrict__ T1,
    const unsigned short* __restrict__ T2,
    const unsigned short* __restrict__ Wt, const float* __restrict__ E,
    const float* __restrict__ bp, int bp_stride, int o_off,
    const float* __restrict__ state, float* __restrict__ rbuf,
    unsigned short* __restrict__ t0_out, float* __restrict__ out) {
    __shared__ unsigned short Xs[64 * 128];  // [b][k]
    __shared__ unsigned short Ws[64 * 128];  // [o][k]
    const int n = blockIdx.x;
    const int tid = threadIdx.x;
    const int wave = tid >> 6;
    const int lane = tid & 63;
    const int l15 = lane & 15;
    const int quad = lane >> 4;
    const int wn = wave * 16;
    const int o_g = wn + l15;

    float bias = 0.f;
#pragma unroll
    for (int e = 0; e < EDIM; ++e)
        bias += E[n * EDIM + e] * bp[e * bp_stride + o_off + o_g];

    f32x4 acc[4] = {};

    for (int s = 0; s < 3; ++s) {
        const unsigned short* Ts = (s == 0) ? T0 : (s == 1) ? T1 : T2;
        // Xs: one contiguous 16 KB row of Ts
        const unsigned short* xsrc = Ts + (size_t)n * GN;
#pragma unroll
        for (int i = 0; i < 4; ++i) {
            const int off = (wave * 4 + i) * 512;  // shorts
            load_lds16(xsrc + off + lane * 8, &Xs[off]);
        }
        // Ws: 64 rows of 128 shorts (256B each), 4 rows per 1KB DMA
#pragma unroll
        for (int i = 0; i < 4; ++i) {
            const int chunk = wave * 4 + i;              // 0..15
            const int orow = chunk * 4 + (lane >> 4);    // 4 rows/chunk
            const unsigned short* g =
                Wt + ((size_t)n * 64 + orow) * KI + s * 128 + (lane & 15) * 8;
            load_lds16(g, &Ws[chunk * 512]);
        }
        __syncthreads();
#pragma unroll
        for (int ks = 0; ks < 4; ++ks) {
            const half8_t b =
                *(const half8_t*)&Ws[(wn + l15) * 128 + ks * 32 + quad * 8];
#pragma unroll
            for (int mi = 0; mi < 4; ++mi) {
                const half8_t a = *(const half8_t*)&Xs[(mi * 16 + l15) * 128 +
                                                       ks * 32 + quad * 8];
                acc[mi] =
                    __builtin_amdgcn_mfma_f32_16x16x32_f16(a, b, acc[mi], 0, 0, 0);
            }
        }
        __syncthreads();
    }

#pragma unroll
    for (int mi = 0; mi < 4; ++mi) {
#pragma unroll
        for (int r = 0; r < 4; ++r) {
            const int b_g = mi * 16 + quad * 4 + r;
            const float v = acc[mi][r] + bias;
            if (MODE == 0) {
                rbuf[((size_t)n * B_SZ + b_g) * 64 + o_g] = sigmoidf_(v);
            } else if (MODE == 1) {
                const float sv = state[((size_t)b_g * N_NODES + n) * 64 + o_g];
                t0_out[(size_t)n * GN + b_g * 128 + 64 + o_g] =
                    f2h(sigmoidf_(v) * sv);
            } else {
                const float hc = tanhf(v);
                const float rr = rbuf[((size_t)n * B_SZ + b_g) * 64 + o_g];
                const float sv = state[((size_t)b_g * N_NODES + n) * 64 + o_g];
                out[((size_t)b_g * N_NODES + n) * 64 + o_g] =
                    rr * sv + (1.f - rr) * hc;
            }
        }
    }
}

// ---------------------------------------------------------------------------
extern "C" void kernel_launch(void* const* d_in, const int* in_sizes, int n_in,
                              void* d_out, int out_size, void* d_ws,
                              size_t ws_size, hipStream_t stream) {
    const float* x = (const float*)d_in[0];
    const float* state = (const float*)d_in[1];
    const float* E = (const float*)d_in[2];
    const float* gW = (const float*)d_in[3];  // (16,3,128,128)
    const float* gb = (const float*)d_in[4];  // (16,128)
    const float* uW = (const float*)d_in[5];  // (16,3,128,64)
    const float* ub = (const float*)d_in[6];  // (16,64)
    float* out = (float*)d_out;

    char* ws = (char*)d_ws;
    unsigned short* Ah = (unsigned short*)ws;                   // 2 MB
    unsigned short* T0 = (unsigned short*)(ws + 2097152);       // 16.78 MB
    unsigned short* T1 = (unsigned short*)(ws + 18874368);
    unsigned short* T2 = (unsigned short*)(ws + 35651584);
    unsigned short* Wt = (unsigned short*)(ws + 52428800);      // 50.33 MB
    float* rbuf = (float*)(ws + 102760448);                     // 16.78 MB
    // total 119.5 MB

    compute_A_kernel<<<N_NODES, 256, 0, stream>>>(E, Ah);
    build_T0_kernel<<<N_NODES, 256, 0, stream>>>(x, state, T0);

    const dim3 ggrid(8, 64);
    const dim3 dqgrid(12, 2, 32);

    // --- avwgcn #1 (gate) ---
    gemm_graph_kernel<0><<<ggrid, 256, 0, stream>>>(Ah, T0, T0, T1);
    gemm_graph_kernel<1><<<ggrid, 256, 0, stream>>>(Ah, T1, T0, T2);
    // r first (z overwrites T0 state-slice)
    dequant_kernel<<<dqgrid, 256, 0, stream>>>(gW, E, Wt, 128, 64);
    pernode_kernel<0><<<N_NODES, 256, 0, stream>>>(T0, T1, T2, Wt, E, gb, 128,
                                                   64, state, rbuf, T0, out);
    dequant_kernel<<<dqgrid, 256, 0, stream>>>(gW, E, Wt, 128, 0);
    pernode_kernel<1><<<N_NODES, 256, 0, stream>>>(T0, T1, T2, Wt, E, gb, 128,
                                                   0, state, rbuf, T0, out);

    // --- avwgcn #2 (update); T0 now holds candidate = [x, z*state] ---
    gemm_graph_kernel<0><<<ggrid, 256, 0, stream>>>(Ah, T0, T0, T1);
    gemm_graph_kernel<1><<<ggrid, 256, 0, stream>>>(Ah, T1, T0, T2);
    dequant_kernel<<<dqgrid, 256, 0, stream>>>(uW, E, Wt, 64, 0);
    pernode_kernel<2><<<N_NODES, 256, 0, stream>>>(T0, T1, T2, Wt, E, ub, 64,
                                                   0, state, rbuf, T0, out);
}

// Round 6
// 364.221 us; speedup vs baseline: 7.5794x; 1.0359x over previous
//
#include <hip/hip_runtime.h>
#include <math.h>

#define N_NODES 1024
#define B_SZ 64
#define GN 8192      // b*c flattened width of xg slot buffers
#define KI 384       // 3*128
#define EDIM 16

typedef _Float16 half8_t __attribute__((ext_vector_type(8)));
typedef float f32x4 __attribute__((ext_vector_type(4)));

__device__ __forceinline__ unsigned short f2h(float f) {
    _Float16 h = (_Float16)f;
    return *(unsigned short*)&h;
}
__device__ __forceinline__ float h2f(unsigned short u) {
    _Float16 h = *(_Float16*)&u;
    return (float)h;
}
__device__ __forceinline__ float sigmoidf_(float v) {
    return 1.f / (1.f + __expf(-v));
}
// async global->LDS, 16B per lane; lds base must be wave-uniform.
__device__ __forceinline__ void load_lds16(const void* g, void* l) {
    __builtin_amdgcn_global_load_lds(
        (const __attribute__((address_space(1))) void*)g,
        (__attribute__((address_space(3))) void*)l, 16, 0, 0);
}

// ---------------------------------------------------------------------------
// A = softmax(relu(E E^T)) row-wise -> fp16
// ---------------------------------------------------------------------------
__global__ __launch_bounds__(256) void compute_A_kernel(
    const float* __restrict__ E, unsigned short* __restrict__ Ah) {
    __shared__ float red[256];
    const int tid = threadIdx.x;
    const int n = blockIdx.x;
    float en[EDIM];
#pragma unroll
    for (int e = 0; e < EDIM; ++e) en[e] = E[n * EDIM + e];
    float logit[4], lmax = -1e30f;
#pragma unroll
    for (int j = 0; j < 4; ++j) {
        const int m = tid + j * 256;
        float d = 0.f;
#pragma unroll
        for (int e = 0; e < EDIM; ++e) d += en[e] * E[m * EDIM + e];
        d = fmaxf(d, 0.f);
        logit[j] = d;
        lmax = fmaxf(lmax, d);
    }
    red[tid] = lmax;
    __syncthreads();
    for (int s = 128; s > 0; s >>= 1) {
        if (tid < s) red[tid] = fmaxf(red[tid], red[tid + s]);
        __syncthreads();
    }
    lmax = red[0];
    __syncthreads();
    float ex[4], lsum = 0.f;
#pragma unroll
    for (int j = 0; j < 4; ++j) {
        ex[j] = __expf(logit[j] - lmax);
        lsum += ex[j];
    }
    red[tid] = lsum;
    __syncthreads();
    for (int s = 128; s > 0; s >>= 1) {
        if (tid < s) red[tid] += red[tid + s];
        __syncthreads();
    }
    const float inv = 1.f / red[0];
#pragma unroll
    for (int j = 0; j < 4; ++j)
        Ah[n * N_NODES + tid + j * 256] = f2h(ex[j] * inv);
}

// ---------------------------------------------------------------------------
// T0[n][b*128+c] = concat(x,state)[b][n][c]  (fp16)
// ---------------------------------------------------------------------------
__global__ __launch_bounds__(256) void build_T0_kernel(
    const float* __restrict__ x, const float* __restrict__ state,
    unsigned short* __restrict__ T0) {
    const int n = blockIdx.x;
    const int tid = threadIdx.x;
#pragma unroll
    for (int t = 0; t < 32; ++t) {
        const int idx = t * 256 + tid;
        const int c = idx & 127;
        const int b = idx >> 7;
        const float v = (c < 64) ? x[((size_t)b * N_NODES + n) * 64 + c]
                                 : state[((size_t)b * N_NODES + n) * 64 + (c - 64)];
        T0[(size_t)n * GN + idx] = f2h(v);
    }
}

// ---------------------------------------------------------------------------
// T0T[bc][n] = T0[n][bc]  via LDS transpose. grid (ntile=16, b=64).
// (R5 bug fixed: writeout loop now covers all 32 n per (c,half) — j<8.)
// ---------------------------------------------------------------------------
__global__ __launch_bounds__(256) void transpose_T0_kernel(
    const unsigned short* __restrict__ T0, unsigned short* __restrict__ T0T) {
    __shared__ unsigned short Ls[128 * 68];  // [c][n], pad 4
    const int tid = threadIdx.x;
    const int n0 = blockIdx.x * 64;
    const int b = blockIdx.y;
#pragma unroll
    for (int t = 0; t < 4; ++t) {
        const int id = t * 256 + tid;
        const int nl = id >> 4;
        const int c8 = id & 15;
        uint4 v = *(const uint4*)&T0[(size_t)(n0 + nl) * GN + b * 128 + c8 * 8];
        const unsigned short* vp = (const unsigned short*)&v;
#pragma unroll
        for (int j = 0; j < 8; ++j) Ls[(c8 * 8 + j) * 68 + nl] = vp[j];
    }
    __syncthreads();
    const int c = tid >> 1;
    const int half = tid & 1;
#pragma unroll
    for (int j = 0; j < 8; ++j) {
        uint2 v = *(const uint2*)&Ls[c * 68 + half * 32 + j * 4];
        *(uint2*)&T0T[(size_t)(b * 128 + c) * N_NODES + n0 + half * 32 + j * 4] =
            v;
    }
}

// ---------------------------------------------------------------------------
// Graph GEMM: OUT[n][bc] = sum_m A[n][m] * BT[bc][m]   (MODE1: 2*acc - T0)
// All staging via global_load_lds width=16 (both operands k-contiguous).
// MODE0 also writes OUT_T[bc][n] (B-input layout for the next GEMM).
// ---------------------------------------------------------------------------
template <int MODE>
__global__ __launch_bounds__(256) void gemm_graph_kernel(
    const unsigned short* __restrict__ Ah,
    const unsigned short* __restrict__ BT,
    const unsigned short* __restrict__ T0corr,
    unsigned short* __restrict__ OUT, unsigned short* __restrict__ OUT_T) {
    __shared__ union {
        struct {
            unsigned short As[128 * 64];  // [n-local][k]
            unsigned short Bs[128 * 64];  // [bc-local][k]
        } s;
        unsigned short Cs[128 * 136];     // epilogue repack
    } lds;
    const int tid = threadIdx.x;
    const int wave = tid >> 6;
    const int lane = tid & 63;
    const int l15 = lane & 15;
    const int quad = lane >> 4;
    const int wm = (wave >> 1) * 64;
    const int wn = (wave & 1) * 64;
    const int n0 = blockIdx.x * 128;
    const int bc0 = blockIdx.y * 128;

    f32x4 acc[4][4] = {};

    for (int k0 = 0; k0 < N_NODES; k0 += 64) {
#pragma unroll
        for (int i = 0; i < 4; ++i) {
            const int rbase = wave * 32 + i * 8;
            load_lds16(&Ah[(size_t)(n0 + rbase + (lane >> 3)) * N_NODES + k0 +
                           (lane & 7) * 8],
                       &lds.s.As[rbase * 64]);
        }
#pragma unroll
        for (int i = 0; i < 4; ++i) {
            const int rbase = wave * 32 + i * 8;
            load_lds16(&BT[(size_t)(bc0 + rbase + (lane >> 3)) * N_NODES + k0 +
                           (lane & 7) * 8],
                       &lds.s.Bs[rbase * 64]);
        }
        __syncthreads();
#pragma unroll
        for (int ks = 0; ks < 2; ++ks) {
            half8_t a[4], b[4];
#pragma unroll
            for (int mi = 0; mi < 4; ++mi)
                a[mi] = *(const half8_t*)&lds.s.As[(wm + mi * 16 + l15) * 64 +
                                                   ks * 32 + quad * 8];
#pragma unroll
            for (int ni = 0; ni < 4; ++ni)
                b[ni] = *(const half8_t*)&lds.s.Bs[(wn + ni * 16 + l15) * 64 +
                                                   ks * 32 + quad * 8];
#pragma unroll
            for (int mi = 0; mi < 4; ++mi)
#pragma unroll
                for (int ni = 0; ni < 4; ++ni)
                    acc[mi][ni] = __builtin_amdgcn_mfma_f32_16x16x32_f16(
                        a[mi], b[ni], acc[mi][ni], 0, 0, 0);
        }
        __syncthreads();
    }

    // --- epilogue pass 1: straight repack -> OUT[n][bc] ---
#pragma unroll
    for (int mi = 0; mi < 4; ++mi)
#pragma unroll
        for (int ni = 0; ni < 4; ++ni)
#pragma unroll
            for (int r = 0; r < 4; ++r) {
                const int row = wm + mi * 16 + quad * 4 + r;
                const int col = wn + ni * 16 + l15;
                lds.Cs[row * 136 + col] = f2h(acc[mi][ni][r]);
            }
    __syncthreads();
#pragma unroll
    for (int i = 0; i < 8; ++i) {
        const int id = i * 256 + tid;
        const int row = id >> 4;
        const int c8 = id & 15;
        uint4 cv = *(const uint4*)&lds.Cs[row * 136 + c8 * 8];
        const size_t gaddr = (size_t)(n0 + row) * GN + bc0 + c8 * 8;
        if (MODE == 1) {
            uint4 tv = *(const uint4*)&T0corr[gaddr];
            const unsigned short* cp = (const unsigned short*)&cv;
            const unsigned short* tp = (const unsigned short*)&tv;
            union { unsigned short u[8]; uint4 v; } o;
#pragma unroll
            for (int j = 0; j < 8; ++j)
                o.u[j] = f2h(2.f * h2f(cp[j]) - h2f(tp[j]));
            *(uint4*)&OUT[gaddr] = o.v;
        } else {
            *(uint4*)&OUT[gaddr] = cv;
        }
    }

    if (MODE == 0) {
        // --- epilogue pass 2: transposed repack -> OUT_T[bc][n] ---
        __syncthreads();
#pragma unroll
        for (int mi = 0; mi < 4; ++mi)
#pragma unroll
            for (int ni = 0; ni < 4; ++ni)
#pragma unroll
                for (int rp = 0; rp < 2; ++rp) {
                    const int row = wm + mi * 16 + quad * 4 + rp * 2;
                    const int col = wn + ni * 16 + l15;
                    const unsigned int pk =
                        (unsigned int)f2h(acc[mi][ni][rp * 2]) |
                        ((unsigned int)f2h(acc[mi][ni][rp * 2 + 1]) << 16);
                    *(unsigned int*)&lds.Cs[col * 136 + row] = pk;
                }
        __syncthreads();
#pragma unroll
        for (int i = 0; i < 8; ++i) {
            const int id = i * 256 + tid;
            const int bcr = id >> 4;
            const int n8 = id & 15;
            uint4 cv = *(const uint4*)&lds.Cs[bcr * 136 + n8 * 8];
            *(uint4*)&OUT_T[(size_t)(bc0 + bcr) * N_NODES + n0 + n8 * 8] = cv;
        }
    }
}

// ---------------------------------------------------------------------------
// Dequant: Wt[n][o][ki] = sum_e E[n,e]*Wp[e][ki][o]  (fp16, k-contig)
// Pool patch in registers, looped over 32 nodes/block (broadcast E from LDS).
// grid (KI/32, NO/32, 1024/32).
// ---------------------------------------------------------------------------
__global__ __launch_bounds__(256) void dequant_kernel(
    const float* __restrict__ Wp, const float* __restrict__ E,
    unsigned short* __restrict__ Wt, int NO) {
    __shared__ float En[32 * 16];
    const int tid = threadIdx.x;
    const int ki0 = blockIdx.x * 32;
    const int o0 = blockIdx.y * 32;
    const int n0 = blockIdx.z * 32;
    const int o = tid >> 3;
    const int k4 = tid & 7;

#pragma unroll
    for (int t = 0; t < 2; ++t) {
        const int id = t * 256 + tid;
        En[id] = E[(n0 + (id >> 4)) * EDIM + (id & 15)];
    }
    __syncthreads();

    f32x4 w[EDIM];
#pragma unroll
    for (int e = 0; e < EDIM; ++e) {
        f32x4 v;
#pragma unroll
        for (int j = 0; j < 4; ++j)
            v[j] = Wp[(size_t)(e * KI + ki0 + k4 * 4 + j) * NO + o0 + o];
        w[e] = v;
    }

    const size_t wt_base = ((size_t)n0 * NO + (o0 + o)) * KI + ki0 + k4 * 4;
#pragma unroll 4
    for (int nl = 0; nl < 32; ++nl) {
        f32x4 a = {0.f, 0.f, 0.f, 0.f};
#pragma unroll
        for (int e = 0; e < EDIM; ++e) a += w[e] * En[nl * EDIM + e];
        union { unsigned short u[4]; uint2 v; } pk;
#pragma unroll
        for (int j = 0; j < 4; ++j) pk.u[j] = f2h(a[j]);
        *(uint2*)&Wt[wt_base + (size_t)nl * NO * KI] = pk.v;
    }
}

// ---------------------------------------------------------------------------
// Gate per-node GEMM (merged z+r): M=64(b), N=128(o: z=0..63, r=64..127),
// K=384.  z -> T0/T0T state slice (z*state); r -> rbuf.
// ---------------------------------------------------------------------------
__global__ __launch_bounds__(256) void pernode_gate_kernel(
    const unsigned short* __restrict__ T0,
    const unsigned short* __restrict__ T1,
    const unsigned short* __restrict__ T2,
    const unsigned short* __restrict__ Wt, const float* __restrict__ E,
    const float* __restrict__ bp, const float* __restrict__ state,
    float* __restrict__ rbuf, unsigned short* __restrict__ t0_out,
    unsigned short* __restrict__ t0T_out) {
    __shared__ unsigned short Xs[64 * 128];   // [b][k]
    __shared__ unsigned short Ws[128 * 128];  // [o][k]
    const int n = blockIdx.x;
    const int tid = threadIdx.x;
    const int wave = tid >> 6;
    const int lane = tid & 63;
    const int l15 = lane & 15;
    const int quad = lane >> 4;
    const int wn = wave * 32;

    float bias[2];
#pragma unroll
    for (int ni = 0; ni < 2; ++ni) {
        float bv = 0.f;
#pragma unroll
        for (int e = 0; e < EDIM; ++e)
            bv += E[n * EDIM + e] * bp[e * 128 + wn + ni * 16 + l15];
        bias[ni] = bv;
    }

    f32x4 acc[4][2] = {};

    for (int s = 0; s < 3; ++s) {
        const unsigned short* Ts = (s == 0) ? T0 : (s == 1) ? T1 : T2;
        const unsigned short* xsrc = Ts + (size_t)n * GN;
#pragma unroll
        for (int i = 0; i < 4; ++i) {
            const int off = (wave * 4 + i) * 512;
            load_lds16(xsrc + off + lane * 8, &Xs[off]);
        }
#pragma unroll
        for (int i = 0; i < 8; ++i) {
            const int chunk = wave * 8 + i;            // 0..31
            const int orow = chunk * 4 + (lane >> 4);  // 4 o-rows per chunk
            const unsigned short* g =
                Wt + ((size_t)n * 128 + orow) * KI + s * 128 + (lane & 15) * 8;
            load_lds16(g, &Ws[chunk * 512]);
        }
        __syncthreads();
#pragma unroll
        for (int ks = 0; ks < 4; ++ks) {
            half8_t b[2];
#pragma unroll
            for (int ni = 0; ni < 2; ++ni)
                b[ni] = *(const half8_t*)&Ws[(wn + ni * 16 + l15) * 128 +
                                             ks * 32 + quad * 8];
#pragma unroll
            for (int mi = 0; mi < 4; ++mi) {
                const half8_t a = *(const half8_t*)&Xs[(mi * 16 + l15) * 128 +
                                                       ks * 32 + quad * 8];
#pragma unroll
                for (int ni = 0; ni < 2; ++ni)
                    acc[mi][ni] = __builtin_amdgcn_mfma_f32_16x16x32_f16(
                        a, b[ni], acc[mi][ni], 0, 0, 0);
            }
        }
        __syncthreads();
    }

#pragma unroll
    for (int mi = 0; mi < 4; ++mi) {
#pragma unroll
        for (int r = 0; r < 4; ++r) {
            const int b_g = mi * 16 + quad * 4 + r;
#pragma unroll
            for (int ni = 0; ni < 2; ++ni) {
                const int o_g = wn + ni * 16 + l15;
                const float v = sigmoidf_(acc[mi][ni][r] + bias[ni]);
                if (o_g < 64) {  // z -> candidate slice (both layouts)
                    const float sv =
                        state[((size_t)b_g * N_NODES + n) * 64 + o_g];
                    const unsigned short zh = f2h(v * sv);
                    t0_out[(size_t)n * GN + b_g * 128 + 64 + o_g] = zh;
                    t0T_out[(size_t)(b_g * 128 + 64 + o_g) * N_NODES + n] = zh;
                } else {  // r
                    rbuf[((size_t)n * B_SZ + b_g) * 64 + (o_g - 64)] = v;
                }
            }
        }
    }
}

// ---------------------------------------------------------------------------
// Update per-node GEMM: out = r*state + (1-r)*tanh(acc+bias). N=64.
// ---------------------------------------------------------------------------
__global__ __launch_bounds__(256) void pernode_upd_kernel(
    const unsigned short* __restrict__ T0,
    const unsigned short* __restrict__ T1,
    const unsigned short* __restrict__ T2,
    const unsigned short* __restrict__ Wt, const float* __restrict__ E,
    const float* __restrict__ bp, const float* __restrict__ state,
    const float* __restrict__ rbuf, float* __restrict__ out) {
    __shared__ unsigned short Xs[64 * 128];  // [b][k]
    __shared__ unsigned short Ws[64 * 128];  // [o][k]
    const int n = blockIdx.x;
    const int tid = threadIdx.x;
    const int wave = tid >> 6;
    const int lane = tid & 63;
    const int l15 = lane & 15;
    const int quad = lane >> 4;
    const int wn = wave * 16;
    const int o_g = wn + l15;

    float bias = 0.f;
#pragma unroll
    for (int e = 0; e < EDIM; ++e)
        bias += E[n * EDIM + e] * bp[e * 64 + o_g];

    f32x4 acc[4] = {};

    for (int s = 0; s < 3; ++s) {
        const unsigned short* Ts = (s == 0) ? T0 : (s == 1) ? T1 : T2;
        const unsigned short* xsrc = Ts + (size_t)n * GN;
#pragma unroll
        for (int i = 0; i < 4; ++i) {
            const int off = (wave * 4 + i) * 512;
            load_lds16(xsrc + off + lane * 8, &Xs[off]);
        }
#pragma unroll
        for (int i = 0; i < 4; ++i) {
            const int chunk = wave * 4 + i;
            const int orow = chunk * 4 + (lane >> 4);
            const unsigned short* g =
                Wt + ((size_t)n * 64 + orow) * KI + s * 128 + (lane & 15) * 8;
            load_lds16(g, &Ws[chunk * 512]);
        }
        __syncthreads();
#pragma unroll
        for (int ks = 0; ks < 4; ++ks) {
            const half8_t b =
                *(const half8_t*)&Ws[(wn + l15) * 128 + ks * 32 + quad * 8];
#pragma unroll
            for (int mi = 0; mi < 4; ++mi) {
                const half8_t a = *(const half8_t*)&Xs[(mi * 16 + l15) * 128 +
                                                       ks * 32 + quad * 8];
                acc[mi] =
                    __builtin_amdgcn_mfma_f32_16x16x32_f16(a, b, acc[mi], 0, 0, 0);
            }
        }
        __syncthreads();
    }

#pragma unroll
    for (int mi = 0; mi < 4; ++mi) {
#pragma unroll
        for (int r = 0; r < 4; ++r) {
            const int b_g = mi * 16 + quad * 4 + r;
            const float hc = tanhf(acc[mi][r] + bias);
            const float rr = rbuf[((size_t)n * B_SZ + b_g) * 64 + o_g];
            const float sv = state[((size_t)b_g * N_NODES + n) * 64 + o_g];
            out[((size_t)b_g * N_NODES + n) * 64 + o_g] =
                rr * sv + (1.f - rr) * hc;
        }
    }
}

// ---------------------------------------------------------------------------
extern "C" void kernel_launch(void* const* d_in, const int* in_sizes, int n_in,
                              void* d_out, int out_size, void* d_ws,
                              size_t ws_size, hipStream_t stream) {
    const float* x = (const float*)d_in[0];
    const float* state = (const float*)d_in[1];
    const float* E = (const float*)d_in[2];
    const float* gW = (const float*)d_in[3];  // (16,3,128,128)
    const float* gb = (const float*)d_in[4];  // (16,128)
    const float* uW = (const float*)d_in[5];  // (16,3,128,64)
    const float* ub = (const float*)d_in[6];  // (16,64)
    float* out = (float*)d_out;

    char* ws = (char*)d_ws;
    unsigned short* Ah = (unsigned short*)ws;                  //  2.10 MB
    unsigned short* T0 = (unsigned short*)(ws + 2097152);      // 16.78 MB
    unsigned short* T0T = (unsigned short*)(ws + 18874368);    // 16.78 MB
    unsigned short* T1 = (unsigned short*)(ws + 35651584);     // 16.78 MB
    unsigned short* T1T = (unsigned short*)(ws + 52428800);    // 16.78 MB
    unsigned short* T2 = (unsigned short*)(ws + 69206016);     // 16.78 MB
    unsigned short* Wt = (unsigned short*)(ws + 85983232);     // 100.66 MB
    float* rbuf = (float*)(ws + 186646528);                    // 16.78 MB
    // total 203.4 MB (ws = 256 MB)

    compute_A_kernel<<<N_NODES, 256, 0, stream>>>(E, Ah);
    build_T0_kernel<<<N_NODES, 256, 0, stream>>>(x, state, T0);
    transpose_T0_kernel<<<dim3(16, 64), 256, 0, stream>>>(T0, T0T);

    const dim3 ggrid(8, 64);

    // --- avwgcn #1 (gate) ---
    dequant_kernel<<<dim3(12, 4, 32), 256, 0, stream>>>(gW, E, Wt, 128);
    gemm_graph_kernel<0><<<ggrid, 256, 0, stream>>>(Ah, T0T, T0, T1, T1T);
    gemm_graph_kernel<1><<<ggrid, 256, 0, stream>>>(Ah, T1T, T0, T2, (unsigned short*)0);
    pernode_gate_kernel<<<N_NODES, 256, 0, stream>>>(T0, T1, T2, Wt, E, gb,
                                                     state, rbuf, T0, T0T);

    // --- avwgcn #2 (update); T0/T0T now hold candidate = [x, z*state] ---
    dequant_kernel<<<dim3(12, 2, 32), 256, 0, stream>>>(uW, E, Wt, 64);
    gemm_graph_kernel<0><<<ggrid, 256, 0, stream>>>(Ah, T0T, T0, T1, T1T);
    gemm_graph_kernel<1><<<ggrid, 256, 0, stream>>>(Ah, T1T, T0, T2, (unsigned short*)0);
    pernode_upd_kernel<<<N_NODES, 256, 0, stream>>>(T0, T1, T2, Wt, E, ub,
                                                    state, rbuf, out);
}

// Round 7
// 343.646 us; speedup vs baseline: 8.0333x; 1.0599x over previous
//
#include <hip/hip_runtime.h>
#include <math.h>

#define N_NODES 1024
#define B_SZ 64
#define GN 8192      // b*c flattened width of xg slot buffers
#define KI 384       // 3*128
#define EDIM 16

typedef _Float16 half8_t __attribute__((ext_vector_type(8)));
typedef float f32x4 __attribute__((ext_vector_type(4)));

__device__ __forceinline__ unsigned short f2h(float f) {
    _Float16 h = (_Float16)f;
    return *(unsigned short*)&h;
}
__device__ __forceinline__ float h2f(unsigned short u) {
    _Float16 h = *(_Float16*)&u;
    return (float)h;
}
__device__ __forceinline__ float sigmoidf_(float v) {
    return 1.f / (1.f + __expf(-v));
}
// async global->LDS, 16B per lane; lds base must be wave-uniform.
__device__ __forceinline__ void load_lds16(const void* g, void* l) {
    __builtin_amdgcn_global_load_lds(
        (const __attribute__((address_space(1))) void*)g,
        (__attribute__((address_space(3))) void*)l, 16, 0, 0);
}

// ---------------------------------------------------------------------------
// A = softmax(relu(E E^T)) row-wise -> fp16
// ---------------------------------------------------------------------------
__global__ __launch_bounds__(256) void compute_A_kernel(
    const float* __restrict__ E, unsigned short* __restrict__ Ah) {
    __shared__ float red[256];
    const int tid = threadIdx.x;
    const int n = blockIdx.x;
    float en[EDIM];
#pragma unroll
    for (int e = 0; e < EDIM; ++e) en[e] = E[n * EDIM + e];
    float logit[4], lmax = -1e30f;
#pragma unroll
    for (int j = 0; j < 4; ++j) {
        const int m = tid + j * 256;
        float d = 0.f;
#pragma unroll
        for (int e = 0; e < EDIM; ++e) d += en[e] * E[m * EDIM + e];
        d = fmaxf(d, 0.f);
        logit[j] = d;
        lmax = fmaxf(lmax, d);
    }
    red[tid] = lmax;
    __syncthreads();
    for (int s = 128; s > 0; s >>= 1) {
        if (tid < s) red[tid] = fmaxf(red[tid], red[tid + s]);
        __syncthreads();
    }
    lmax = red[0];
    __syncthreads();
    float ex[4], lsum = 0.f;
#pragma unroll
    for (int j = 0; j < 4; ++j) {
        ex[j] = __expf(logit[j] - lmax);
        lsum += ex[j];
    }
    red[tid] = lsum;
    __syncthreads();
    for (int s = 128; s > 0; s >>= 1) {
        if (tid < s) red[tid] += red[tid + s];
        __syncthreads();
    }
    const float inv = 1.f / red[0];
#pragma unroll
    for (int j = 0; j < 4; ++j)
        Ah[n * N_NODES + tid + j * 256] = f2h(ex[j] * inv);
}

// ---------------------------------------------------------------------------
// T0[n][b*128+c] = concat(x,state)[b][n][c]  (fp16)
// ---------------------------------------------------------------------------
__global__ __launch_bounds__(256) void build_T0_kernel(
    const float* __restrict__ x, const float* __restrict__ state,
    unsigned short* __restrict__ T0) {
    const int n = blockIdx.x;
    const int tid = threadIdx.x;
#pragma unroll
    for (int t = 0; t < 32; ++t) {
        const int idx = t * 256 + tid;
        const int c = idx & 127;
        const int b = idx >> 7;
        const float v = (c < 64) ? x[((size_t)b * N_NODES + n) * 64 + c]
                                 : state[((size_t)b * N_NODES + n) * 64 + (c - 64)];
        T0[(size_t)n * GN + idx] = f2h(v);
    }
}

// ---------------------------------------------------------------------------
// T0T[bc][n] = T0[n][bc]  via LDS transpose. grid (ntile=16, b=64).
// ---------------------------------------------------------------------------
__global__ __launch_bounds__(256) void transpose_T0_kernel(
    const unsigned short* __restrict__ T0, unsigned short* __restrict__ T0T) {
    __shared__ unsigned short Ls[128 * 68];  // [c][n], pad 4
    const int tid = threadIdx.x;
    const int n0 = blockIdx.x * 64;
    const int b = blockIdx.y;
#pragma unroll
    for (int t = 0; t < 4; ++t) {
        const int id = t * 256 + tid;
        const int nl = id >> 4;
        const int c8 = id & 15;
        uint4 v = *(const uint4*)&T0[(size_t)(n0 + nl) * GN + b * 128 + c8 * 8];
        const unsigned short* vp = (const unsigned short*)&v;
#pragma unroll
        for (int j = 0; j < 8; ++j) Ls[(c8 * 8 + j) * 68 + nl] = vp[j];
    }
    __syncthreads();
    const int c = tid >> 1;
    const int half = tid & 1;
#pragma unroll
    for (int j = 0; j < 8; ++j) {
        uint2 v = *(const uint2*)&Ls[c * 68 + half * 32 + j * 4];
        *(uint2*)&T0T[(size_t)(b * 128 + c) * N_NODES + n0 + half * 32 + j * 4] =
            v;
    }
}

// ---------------------------------------------------------------------------
// Graph GEMM: OUT[n][bc] = sum_m A[n][m] * BT[bc][m]   (MODE1: 2*acc - T0)
// Staging via global_load_lds with XOR-swizzled ksegs:
//   LDS[row][slot] = global[row][slot ^ (row&7)]   (rows of 8 ksegs = 64 sh)
// Fragment read at slot = K ^ (row&7) -> 2-way banking (free).
// MODE0 also writes OUT_T[bc][n] (B-input layout for the next GEMM).
// ---------------------------------------------------------------------------
template <int MODE>
__global__ __launch_bounds__(256) void gemm_graph_kernel(
    const unsigned short* __restrict__ Ah,
    const unsigned short* __restrict__ BT,
    const unsigned short* __restrict__ T0corr,
    unsigned short* __restrict__ OUT, unsigned short* __restrict__ OUT_T) {
    __shared__ union {
        struct {
            unsigned short As[128 * 64];  // [n-local][k] swizzled
            unsigned short Bs[128 * 64];  // [bc-local][k] swizzled
        } s;
        unsigned short Cs[128 * 136];     // epilogue repack
    } lds;
    const int tid = threadIdx.x;
    const int wave = tid >> 6;
    const int lane = tid & 63;
    const int l15 = lane & 15;
    const int quad = lane >> 4;
    const int wm = (wave >> 1) * 64;
    const int wn = (wave & 1) * 64;
    const int n0 = blockIdx.x * 128;
    const int bc0 = blockIdx.y * 128;
    const int lr = lane >> 3;              // row within 8-row DMA chunk
    const int lsw = (lane & 7) ^ lr;       // swizzled kseg for staging

    f32x4 acc[4][4] = {};

    for (int k0 = 0; k0 < N_NODES; k0 += 64) {
#pragma unroll
        for (int i = 0; i < 4; ++i) {
            const int rbase = wave * 32 + i * 8;
            load_lds16(&Ah[(size_t)(n0 + rbase + lr) * N_NODES + k0 + lsw * 8],
                       &lds.s.As[rbase * 64]);
        }
#pragma unroll
        for (int i = 0; i < 4; ++i) {
            const int rbase = wave * 32 + i * 8;
            load_lds16(&BT[(size_t)(bc0 + rbase + lr) * N_NODES + k0 + lsw * 8],
                       &lds.s.Bs[rbase * 64]);
        }
        __syncthreads();
#pragma unroll
        for (int ks = 0; ks < 2; ++ks) {
            const int K = ks * 4 + quad;           // kseg index 0..7
            const int slot = (K ^ (l15 & 7)) * 8;  // row&7 == l15&7
            half8_t a[4], b[4];
#pragma unroll
            for (int mi = 0; mi < 4; ++mi)
                a[mi] = *(const half8_t*)&lds.s
                             .As[(wm + mi * 16 + l15) * 64 + slot];
#pragma unroll
            for (int ni = 0; ni < 4; ++ni)
                b[ni] = *(const half8_t*)&lds.s
                             .Bs[(wn + ni * 16 + l15) * 64 + slot];
#pragma unroll
            for (int mi = 0; mi < 4; ++mi)
#pragma unroll
                for (int ni = 0; ni < 4; ++ni)
                    acc[mi][ni] = __builtin_amdgcn_mfma_f32_16x16x32_f16(
                        a[mi], b[ni], acc[mi][ni], 0, 0, 0);
        }
        __syncthreads();
    }

    // --- epilogue pass 1: straight repack -> OUT[n][bc] ---
#pragma unroll
    for (int mi = 0; mi < 4; ++mi)
#pragma unroll
        for (int ni = 0; ni < 4; ++ni)
#pragma unroll
            for (int r = 0; r < 4; ++r) {
                const int row = wm + mi * 16 + quad * 4 + r;
                const int col = wn + ni * 16 + l15;
                lds.Cs[row * 136 + col] = f2h(acc[mi][ni][r]);
            }
    __syncthreads();
#pragma unroll
    for (int i = 0; i < 8; ++i) {
        const int id = i * 256 + tid;
        const int row = id >> 4;
        const int c8 = id & 15;
        uint4 cv = *(const uint4*)&lds.Cs[row * 136 + c8 * 8];
        const size_t gaddr = (size_t)(n0 + row) * GN + bc0 + c8 * 8;
        if (MODE == 1) {
            uint4 tv = *(const uint4*)&T0corr[gaddr];
            const unsigned short* cp = (const unsigned short*)&cv;
            const unsigned short* tp = (const unsigned short*)&tv;
            union { unsigned short u[8]; uint4 v; } o;
#pragma unroll
            for (int j = 0; j < 8; ++j)
                o.u[j] = f2h(2.f * h2f(cp[j]) - h2f(tp[j]));
            *(uint4*)&OUT[gaddr] = o.v;
        } else {
            *(uint4*)&OUT[gaddr] = cv;
        }
    }

    if (MODE == 0) {
        // --- epilogue pass 2: transposed repack -> OUT_T[bc][n] ---
        __syncthreads();
#pragma unroll
        for (int mi = 0; mi < 4; ++mi)
#pragma unroll
            for (int ni = 0; ni < 4; ++ni)
#pragma unroll
                for (int rp = 0; rp < 2; ++rp) {
                    const int row = wm + mi * 16 + quad * 4 + rp * 2;
                    const int col = wn + ni * 16 + l15;
                    const unsigned int pk =
                        (unsigned int)f2h(acc[mi][ni][rp * 2]) |
                        ((unsigned int)f2h(acc[mi][ni][rp * 2 + 1]) << 16);
                    *(unsigned int*)&lds.Cs[col * 136 + row] = pk;
                }
        __syncthreads();
#pragma unroll
        for (int i = 0; i < 8; ++i) {
            const int id = i * 256 + tid;
            const int bcr = id >> 4;
            const int n8 = id & 15;
            uint4 cv = *(const uint4*)&lds.Cs[bcr * 136 + n8 * 8];
            *(uint4*)&OUT_T[(size_t)(bc0 + bcr) * N_NODES + n0 + n8 * 8] = cv;
        }
    }
}

// ---------------------------------------------------------------------------
// Dequant: Wt[n][o][ki] = sum_e E[n,e]*Wp[e][ki][o]  (fp16, k-contig)
// Pool patch in registers, looped over 32 nodes/block.
// ---------------------------------------------------------------------------
__global__ __launch_bounds__(256) void dequant_kernel(
    const float* __restrict__ Wp, const float* __restrict__ E,
    unsigned short* __restrict__ Wt, int NO) {
    __shared__ float En[32 * 16];
    const int tid = threadIdx.x;
    const int ki0 = blockIdx.x * 32;
    const int o0 = blockIdx.y * 32;
    const int n0 = blockIdx.z * 32;
    const int o = tid >> 3;
    const int k4 = tid & 7;

#pragma unroll
    for (int t = 0; t < 2; ++t) {
        const int id = t * 256 + tid;
        En[id] = E[(n0 + (id >> 4)) * EDIM + (id & 15)];
    }
    __syncthreads();

    f32x4 w[EDIM];
#pragma unroll
    for (int e = 0; e < EDIM; ++e) {
        f32x4 v;
#pragma unroll
        for (int j = 0; j < 4; ++j)
            v[j] = Wp[(size_t)(e * KI + ki0 + k4 * 4 + j) * NO + o0 + o];
        w[e] = v;
    }

    const size_t wt_base = ((size_t)n0 * NO + (o0 + o)) * KI + ki0 + k4 * 4;
#pragma unroll 4
    for (int nl = 0; nl < 32; ++nl) {
        f32x4 a = {0.f, 0.f, 0.f, 0.f};
#pragma unroll
        for (int e = 0; e < EDIM; ++e) a += w[e] * En[nl * EDIM + e];
        union { unsigned short u[4]; uint2 v; } pk;
#pragma unroll
        for (int j = 0; j < 4; ++j) pk.u[j] = f2h(a[j]);
        *(uint2*)&Wt[wt_base + (size_t)nl * NO * KI] = pk.v;
    }
}

// ---------------------------------------------------------------------------
// Gate per-node GEMM (merged z+r): M=64(b), N=128(o: z=0..63, r=64..127),
// K=384.  Rows of 16 ksegs: swizzle kseg ^ (row&15) at stage + read.
// ---------------------------------------------------------------------------
__global__ __launch_bounds__(256) void pernode_gate_kernel(
    const unsigned short* __restrict__ T0,
    const unsigned short* __restrict__ T1,
    const unsigned short* __restrict__ T2,
    const unsigned short* __restrict__ Wt, const float* __restrict__ E,
    const float* __restrict__ bp, const float* __restrict__ state,
    float* __restrict__ rbuf, unsigned short* __restrict__ t0_out,
    unsigned short* __restrict__ t0T_out) {
    __shared__ unsigned short Xs[64 * 128];   // [b][k] swizzled
    __shared__ unsigned short Ws[128 * 128];  // [o][k] swizzled
    const int n = blockIdx.x;
    const int tid = threadIdx.x;
    const int wave = tid >> 6;
    const int lane = tid & 63;
    const int l15 = lane & 15;
    const int quad = lane >> 4;
    const int wn = wave * 32;
    const int lr4 = lane >> 4;  // row within 4-row DMA chunk

    float bias[2];
#pragma unroll
    for (int ni = 0; ni < 2; ++ni) {
        float bv = 0.f;
#pragma unroll
        for (int e = 0; e < EDIM; ++e)
            bv += E[n * EDIM + e] * bp[e * 128 + wn + ni * 16 + l15];
        bias[ni] = bv;
    }

    f32x4 acc[4][2] = {};

    for (int s = 0; s < 3; ++s) {
        const unsigned short* Ts = (s == 0) ? T0 : (s == 1) ? T1 : T2;
        const unsigned short* xsrc = Ts + (size_t)n * GN;
#pragma unroll
        for (int i = 0; i < 4; ++i) {
            const int chunk = wave * 4 + i;
            const int row = chunk * 4 + lr4;
            const int sw = (lane & 15) ^ (row & 15);
            load_lds16(xsrc + row * 128 + sw * 8, &Xs[chunk * 512]);
        }
#pragma unroll
        for (int i = 0; i < 8; ++i) {
            const int chunk = wave * 8 + i;            // 0..31
            const int orow = chunk * 4 + lr4;
            const int sw = (lane & 15) ^ (orow & 15);
            load_lds16(Wt + ((size_t)n * 128 + orow) * KI + s * 128 + sw * 8,
                       &Ws[chunk * 512]);
        }
        __syncthreads();
#pragma unroll
        for (int ks = 0; ks < 4; ++ks) {
            const int slot = ((ks * 4 + quad) ^ l15) * 8;  // row&15 == l15
            half8_t b[2];
#pragma unroll
            for (int ni = 0; ni < 2; ++ni)
                b[ni] = *(const half8_t*)&Ws[(wn + ni * 16 + l15) * 128 + slot];
#pragma unroll
            for (int mi = 0; mi < 4; ++mi) {
                const half8_t a =
                    *(const half8_t*)&Xs[(mi * 16 + l15) * 128 + slot];
#pragma unroll
                for (int ni = 0; ni < 2; ++ni)
                    acc[mi][ni] = __builtin_amdgcn_mfma_f32_16x16x32_f16(
                        a, b[ni], acc[mi][ni], 0, 0, 0);
            }
        }
        __syncthreads();
    }

#pragma unroll
    for (int mi = 0; mi < 4; ++mi) {
#pragma unroll
        for (int r = 0; r < 4; ++r) {
            const int b_g = mi * 16 + quad * 4 + r;
#pragma unroll
            for (int ni = 0; ni < 2; ++ni) {
                const int o_g = wn + ni * 16 + l15;
                const float v = sigmoidf_(acc[mi][ni][r] + bias[ni]);
                if (o_g < 64) {  // z -> candidate slice (both layouts)
                    const float sv =
                        state[((size_t)b_g * N_NODES + n) * 64 + o_g];
                    const unsigned short zh = f2h(v * sv);
                    t0_out[(size_t)n * GN + b_g * 128 + 64 + o_g] = zh;
                    t0T_out[(size_t)(b_g * 128 + 64 + o_g) * N_NODES + n] = zh;
                } else {  // r
                    rbuf[((size_t)n * B_SZ + b_g) * 64 + (o_g - 64)] = v;
                }
            }
        }
    }
}

// ---------------------------------------------------------------------------
// Update per-node GEMM: out = r*state + (1-r)*tanh(acc+bias). N=64.
// ---------------------------------------------------------------------------
__global__ __launch_bounds__(256) void pernode_upd_kernel(
    const unsigned short* __restrict__ T0,
    const unsigned short* __restrict__ T1,
    const unsigned short* __restrict__ T2,
    const unsigned short* __restrict__ Wt, const float* __restrict__ E,
    const float* __restrict__ bp, const float* __restrict__ state,
    const float* __restrict__ rbuf, float* __restrict__ out) {
    __shared__ unsigned short Xs[64 * 128];  // [b][k] swizzled
    __shared__ unsigned short Ws[64 * 128];  // [o][k] swizzled
    const int n = blockIdx.x;
    const int tid = threadIdx.x;
    const int wave = tid >> 6;
    const int lane = tid & 63;
    const int l15 = lane & 15;
    const int quad = lane >> 4;
    const int wn = wave * 16;
    const int o_g = wn + l15;
    const int lr4 = lane >> 4;

    float bias = 0.f;
#pragma unroll
    for (int e = 0; e < EDIM; ++e)
        bias += E[n * EDIM + e] * bp[e * 64 + o_g];

    f32x4 acc[4] = {};

    for (int s = 0; s < 3; ++s) {
        const unsigned short* Ts = (s == 0) ? T0 : (s == 1) ? T1 : T2;
        const unsigned short* xsrc = Ts + (size_t)n * GN;
#pragma unroll
        for (int i = 0; i < 4; ++i) {
            const int chunk = wave * 4 + i;
            const int row = chunk * 4 + lr4;
            const int sw = (lane & 15) ^ (row & 15);
            load_lds16(xsrc + row * 128 + sw * 8, &Xs[chunk * 512]);
        }
#pragma unroll
        for (int i = 0; i < 4; ++i) {
            const int chunk = wave * 4 + i;
            const int orow = chunk * 4 + lr4;
            const int sw = (lane & 15) ^ (orow & 15);
            load_lds16(Wt + ((size_t)n * 64 + orow) * KI + s * 128 + sw * 8,
                       &Ws[chunk * 512]);
        }
        __syncthreads();
#pragma unroll
        for (int ks = 0; ks < 4; ++ks) {
            const int slot = ((ks * 4 + quad) ^ l15) * 8;
            const half8_t b = *(const half8_t*)&Ws[(wn + l15) * 128 + slot];
#pragma unroll
            for (int mi = 0; mi < 4; ++mi) {
                const half8_t a =
                    *(const half8_t*)&Xs[(mi * 16 + l15) * 128 + slot];
                acc[mi] =
                    __builtin_amdgcn_mfma_f32_16x16x32_f16(a, b, acc[mi], 0, 0, 0);
            }
        }
        __syncthreads();
    }

#pragma unroll
    for (int mi = 0; mi < 4; ++mi) {
#pragma unroll
        for (int r = 0; r < 4; ++r) {
            const int b_g = mi * 16 + quad * 4 + r;
            const float hc = tanhf(acc[mi][r] + bias);
            const float rr = rbuf[((size_t)n * B_SZ + b_g) * 64 + o_g];
            const float sv = state[((size_t)b_g * N_NODES + n) * 64 + o_g];
            out[((size_t)b_g * N_NODES + n) * 64 + o_g] =
                rr * sv + (1.f - rr) * hc;
        }
    }
}

// ---------------------------------------------------------------------------
extern "C" void kernel_launch(void* const* d_in, const int* in_sizes, int n_in,
                              void* d_out, int out_size, void* d_ws,
                              size_t ws_size, hipStream_t stream) {
    const float* x = (const float*)d_in[0];
    const float* state = (const float*)d_in[1];
    const float* E = (const float*)d_in[2];
    const float* gW = (const float*)d_in[3];  // (16,3,128,128)
    const float* gb = (const float*)d_in[4];  // (16,128)
    const float* uW = (const float*)d_in[5];  // (16,3,128,64)
    const float* ub = (const float*)d_in[6];  // (16,64)
    float* out = (float*)d_out;

    char* ws = (char*)d_ws;
    unsigned short* Ah = (unsigned short*)ws;                  //  2.10 MB
    unsigned short* T0 = (unsigned short*)(ws + 2097152);      // 16.78 MB
    unsigned short* T0T = (unsigned short*)(ws + 18874368);    // 16.78 MB
    unsigned short* T1 = (unsigned short*)(ws + 35651584);     // 16.78 MB
    unsigned short* T1T = (unsigned short*)(ws + 52428800);    // 16.78 MB
    unsigned short* T2 = (unsigned short*)(ws + 69206016);     // 16.78 MB
    unsigned short* Wt = (unsigned short*)(ws + 85983232);     // 100.66 MB
    float* rbuf = (float*)(ws + 186646528);                    // 16.78 MB
    // total 203.4 MB (ws = 256 MB)

    compute_A_kernel<<<N_NODES, 256, 0, stream>>>(E, Ah);
    build_T0_kernel<<<N_NODES, 256, 0, stream>>>(x, state, T0);
    transpose_T0_kernel<<<dim3(16, 64), 256, 0, stream>>>(T0, T0T);

    const dim3 ggrid(8, 64);

    // --- avwgcn #1 (gate) ---
    dequant_kernel<<<dim3(12, 4, 32), 256, 0, stream>>>(gW, E, Wt, 128);
    gemm_graph_kernel<0><<<ggrid, 256, 0, stream>>>(Ah, T0T, T0, T1, T1T);
    gemm_graph_kernel<1><<<ggrid, 256, 0, stream>>>(Ah, T1T, T0, T2, (unsigned short*)0);
    pernode_gate_kernel<<<N_NODES, 256, 0, stream>>>(T0, T1, T2, Wt, E, gb,
                                                     state, rbuf, T0, T0T);

    // --- avwgcn #2 (update); T0/T0T now hold candidate = [x, z*state] ---
    dequant_kernel<<<dim3(12, 2, 32), 256, 0, stream>>>(uW, E, Wt, 64);
    gemm_graph_kernel<0><<<ggrid, 256, 0, stream>>>(Ah, T0T, T0, T1, T1T);
    gemm_graph_kernel<1><<<ggrid, 256, 0, stream>>>(Ah, T1T, T0, T2, (unsigned short*)0);
    pernode_upd_kernel<<<N_NODES, 256, 0, stream>>>(T0, T1, T2, Wt, E, ub,
                                                    state, rbuf, out);
}